// Round 15
// baseline (97.892 us; speedup 1.0000x reference)
//
#include <hip/hip_runtime.h>
#include <hip/hip_bf16.h>

// 3-layer GCN, N=100000, E=1000000, dims 64 -> 64 -> 32 -> 16.
// CSR via two-level LDS bucket counting sort (zero global atomics).
// R15: CHUNK 4096->2048 — R14's hist1/place1 ran only 245 blocks on a 256-CU
// chip (1 block/CU, no inter-block latency hiding). 489 blocks fills ~2/CU.
// MAXNSC 128->256 (T=382K, nsc=187). All consumer kernels byte-identical.

typedef short bf16x8 __attribute__((ext_vector_type(8)));
typedef float f32x4 __attribute__((ext_vector_type(4)));

__device__ __forceinline__ float lrelu(float v) { return v > 0.0f ? v : 0.25f * v; }
__device__ __forceinline__ float bflo(unsigned u) { return __uint_as_float(u << 16); }
__device__ __forceinline__ float bfhi(unsigned u) { return __uint_as_float(u & 0xffff0000u); }
__device__ __forceinline__ unsigned short f2bf(float f) {          // round-to-nearest-even
    unsigned u = __float_as_uint(f);
    return (unsigned short)((u + 0x7fffu + ((u >> 16) & 1u)) >> 16);
}
__device__ __forceinline__ unsigned packbf(float a, float b) {
    return (unsigned)f2bf(a) | ((unsigned)f2bf(b) << 16);
}

// ---------------- bucket counting-sort CSR build ----------------

constexpr int SCAN_T = 256;
constexpr int SCAN_PER = 8;
constexpr int SCAN_CHUNK = SCAN_T * SCAN_PER;  // 2048 (scan1 granularity; getI >>11)
constexpr int CHUNK = 2048;                    // edges per hist/place1 block (R15: GPU fill)
constexpr int BKT_BITS = 7;
constexpr int BKTSZ = 128;                     // nodes per bucket
constexpr int MAXBKT = 1024;                   // LDS bins (N <= 131072)
constexpr int MAXNSC = 256;                    // max scan1 chunks (T <= 524288)
constexpr int P2CAP = 2048;                    // place2 LDS edge cap (avg 1280/bucket)

__device__ __forceinline__ void build_bofs(const int* __restrict__ bsum, int nsc,
                                           int* tmp, int* bofs) {
    int t = threadIdx.x;
    int v = (t < MAXNSC && t < nsc) ? bsum[t] : 0;
    if (t < MAXNSC) tmp[t] = v;
    __syncthreads();
    for (int off = 1; off < MAXNSC; off <<= 1) {
        int add = (t < MAXNSC && t >= off) ? tmp[t - off] : 0;
        __syncthreads();
        if (t < MAXNSC) tmp[t] += add;
        __syncthreads();
    }
    if (t < MAXNSC) bofs[t] = tmp[t] - v;   // exclusive
    __syncthreads();
}

__device__ __forceinline__ int getI(const int* __restrict__ I,
                                    const int* __restrict__ bofs, size_t idx) {
    return I[idx] + bofs[idx >> 11];    // 2048-element scan chunks
}

__global__ void __launch_bounds__(256)
hist1_kernel(const int* __restrict__ row, int* __restrict__ hists,
             int E, int nbkt, int NB) {
    __shared__ int hist[MAXBKT];
    for (int i = threadIdx.x; i < nbkt; i += 256) hist[i] = 0;
    __syncthreads();
    int e0 = blockIdx.x * CHUNK;
    int e1 = min(e0 + CHUNK, E);
    for (int e = e0 + threadIdx.x; e < e1; e += 256)
        atomicAdd(&hist[row[e] >> BKT_BITS], 1);            // LDS atomic
    __syncthreads();
    for (int i = threadIdx.x; i < nbkt; i += 256)
        hists[(size_t)i * NB + blockIdx.x] = hist[i];
}

__global__ void __launch_bounds__(SCAN_T)
scan1_kernel(int* __restrict__ I, int* __restrict__ bsum, int T) {
    __shared__ int lds[SCAN_T];
    int t = threadIdx.x;
    int base = blockIdx.x * SCAN_CHUNK + t * SCAN_PER;
    int v[SCAN_PER];
    int run = 0;
#pragma unroll
    for (int j = 0; j < SCAN_PER; ++j) {
        int i = base + j;
        run += (i < T) ? I[i] : 0;
        v[j] = run;
    }
    lds[t] = run;
    __syncthreads();
    for (int off = 1; off < SCAN_T; off <<= 1) {
        int add = (t >= off) ? lds[t - off] : 0;
        __syncthreads();
        lds[t] += add;
        __syncthreads();
    }
    int excl = lds[t] - run;
#pragma unroll
    for (int j = 0; j < SCAN_PER; ++j) {
        int i = base + j;
        if (i < T) I[i] = v[j] + excl;
    }
    if (t == SCAN_T - 1) bsum[blockIdx.x] = lds[t];
}

// ---------------- fused: place1 (blocks [0,NB)) + MFMA gemm1 (blocks [NB,..)) ----
// LDS arena sized for max(place1: 2048+1024+512 ints, gemm1: 4096 floats' worth).

__global__ void __launch_bounds__(256)
fused_place1_gemm1_kernel(const int* __restrict__ row, const int* __restrict__ col,
                          const float* __restrict__ w, const int* __restrict__ I,
                          const int* __restrict__ bsum, int nsc, int2* __restrict__ eb1,
                          int E, int nbkt, int NB,
                          const float* __restrict__ x, const float* __restrict__ W1,
                          __hip_bfloat16* __restrict__ s1, int N) {
    __shared__ int arena[4096];   // 16 KB, both roles fit
    if ((int)blockIdx.x < NB) {
        // ---- place1 role ----
        int* srow = arena;                       // CHUNK ints
        int* hist = arena + CHUNK;               // MAXBKT ints
        int* tmp  = arena + CHUNK + MAXBKT;      // MAXNSC ints
        int* bofs = tmp + MAXNSC;                // MAXNSC ints (tot 2048+1024+512=3584)
        build_bofs(bsum, nsc, tmp, bofs);
        for (int i = threadIdx.x; i < nbkt; i += 256) hist[i] = 0;
        int e0 = blockIdx.x * CHUNK;
        int e1 = min(e0 + CHUNK, E);
        for (int e = e0 + threadIdx.x; e < e1; e += 256) srow[e - e0] = row[e];
        __syncthreads();
        for (int i = threadIdx.x; i < e1 - e0; i += 256)
            atomicAdd(&hist[srow[i] >> BKT_BITS], 1);
        __syncthreads();
        for (int i = threadIdx.x; i < nbkt; i += 256) {
            size_t idx = (size_t)i * NB + blockIdx.x;
            hist[i] = getI(I, bofs, idx) - hist[i];
        }
        __syncthreads();
        for (int e = e0 + threadIdx.x; e < e1; e += 256) {
            int r = srow[e - e0];
            int pos = atomicAdd(&hist[r >> BKT_BITS], 1);    // LDS atomic, returns slot
            eb1[pos] = make_int2(((r & (BKTSZ - 1)) << 20) | col[e], __float_as_int(w[e]));
        }
        return;
    }
    // ---- MFMA gemm1 role: s1 = bf16(x) @ W1, K=64, M=64, NT=2 ----
    constexpr int K = 64, M = 64, NT = 2, CT = M / 16, KH = K / 32;
    float* Ws = reinterpret_cast<float*>(arena);
    for (int i = threadIdx.x; i < K * M / 4; i += 256)
        reinterpret_cast<float4*>(Ws)[i] = reinterpret_cast<const float4*>(W1)[i];
    __syncthreads();
    const int lane = threadIdx.x & 63;
    const int wave = threadIdx.x >> 6;
    const int lrow = lane & 15;
    const int lgrp = lane >> 4;

    bf16x8 bfrag[CT][KH];
#pragma unroll
    for (int ct = 0; ct < CT; ++ct)
#pragma unroll
        for (int kh = 0; kh < KH; ++kh)
#pragma unroll
            for (int j = 0; j < 8; ++j)
                bfrag[ct][kh][j] =
                    (short)f2bf(Ws[(kh * 32 + lgrp * 8 + j) * M + ct * 16 + lrow]);

    unsigned short* outs = (unsigned short*)s1;
    const int wave_base = ((int)blockIdx.x - NB) * (4 * NT * 16) + wave * (NT * 16);
#pragma unroll
    for (int t = 0; t < NT; ++t) {
        int nb = wave_base + t * 16;
        if (nb >= N) break;
        int arow = nb + lrow;
        bf16x8 afrag[KH];
#pragma unroll
        for (int kh = 0; kh < KH; ++kh) {
            const float* ap = x + (size_t)arow * K + kh * 32 + lgrp * 8;
            float4 u0 = *reinterpret_cast<const float4*>(ap);
            float4 u1 = *reinterpret_cast<const float4*>(ap + 4);
            afrag[kh][0] = (short)f2bf(u0.x); afrag[kh][1] = (short)f2bf(u0.y);
            afrag[kh][2] = (short)f2bf(u0.z); afrag[kh][3] = (short)f2bf(u0.w);
            afrag[kh][4] = (short)f2bf(u1.x); afrag[kh][5] = (short)f2bf(u1.y);
            afrag[kh][6] = (short)f2bf(u1.z); afrag[kh][7] = (short)f2bf(u1.w);
        }
        f32x4 acc[CT];
#pragma unroll
        for (int ct = 0; ct < CT; ++ct) { acc[ct][0]=0.f; acc[ct][1]=0.f; acc[ct][2]=0.f; acc[ct][3]=0.f; }
#pragma unroll
        for (int ct = 0; ct < CT; ++ct)
#pragma unroll
            for (int kh = 0; kh < KH; ++kh)
                acc[ct] = __builtin_amdgcn_mfma_f32_16x16x32_bf16(
                    afrag[kh], bfrag[ct][kh], acc[ct], 0, 0, 0);
#pragma unroll
        for (int ct = 0; ct < CT; ++ct)
#pragma unroll
            for (int r = 0; r < 4; ++r) {
                int orow = nb + lgrp * 4 + r;
                outs[(size_t)orow * M + ct * 16 + lrow] = f2bf(acc[ct][r]);
            }
    }
}

// one block per bucket: LDS-staged single-pass per-node CSR; emits packed edges[] + rs[].
__global__ void __launch_bounds__(256)
place2_kernel(const int2* __restrict__ eb1, const int* __restrict__ I,
              const int* __restrict__ bsum, int nsc, unsigned* __restrict__ edges,
              int* __restrict__ rs, int N, int NB) {
    __shared__ int2 se[P2CAP];        // 16 KB staged edges
    __shared__ int hist[BKTSZ];
    __shared__ int scanv[BKTSZ];
    __shared__ int tmp[MAXNSC];
    __shared__ int bofs[MAXNSC];
    build_bofs(bsum, nsc, tmp, bofs);
    int b = blockIdx.x;
    int t = threadIdx.x;
    int bstart = (b == 0) ? 0 : getI(I, bofs, (size_t)b * NB - 1);
    int bend   = getI(I, bofs, (size_t)(b + 1) * NB - 1);
    int cnt = bend - bstart;
    bool inlds = (cnt <= P2CAP);
    if (inlds)
        for (int e = t; e < cnt; e += 256) se[e] = eb1[bstart + e];   // one coalesced read
    if (t < BKTSZ) hist[t] = 0;
    __syncthreads();
    for (int e = t; e < cnt; e += 256) {
        int ex = inlds ? se[e].x : eb1[bstart + e].x;
        atomicAdd(&hist[(ex >> 20) & (BKTSZ - 1)], 1);
    }
    __syncthreads();
    int cval = (t < BKTSZ) ? hist[t] : 0;
    if (t < BKTSZ) scanv[t] = cval;
    __syncthreads();
    for (int off = 1; off < BKTSZ; off <<= 1) {
        int add = (t < BKTSZ && t >= off) ? scanv[t - off] : 0;
        __syncthreads();
        if (t < BKTSZ) scanv[t] += add;
        __syncthreads();
    }
    if (t < BKTSZ) {
        int gnode = b * BKTSZ + t;
        if (gnode < N) rs[gnode] = bstart + scanv[t];        // inclusive ends
        hist[t] = bstart + scanv[t] - cval;                  // node base for placing
    }
    __syncthreads();
    for (int e = t; e < cnt; e += 256) {
        int2 ev = inlds ? se[e] : eb1[bstart + e];
        int lrow = (ev.x >> 20) & (BKTSZ - 1);
        float w = __int_as_float(ev.y);
        unsigned q = (unsigned)(w * 32768.f + 0.5f);
        q = q > 32767u ? 32767u : q;
        unsigned packed = (q << 17) | (unsigned)(ev.x & 0x1FFFF);   // w15 | col17
        int pos = atomicAdd(&hist[lrow], 1);                 // LDS atomic
        edges[pos] = packed;
    }
}

// ---------------- fused agg_k + gemm_{k+1} (unchanged) ----------------

template <int MA, int GA, int MB>
__global__ void __launch_bounds__(256)
fused_agg_gemm_kernel(const int* __restrict__ rs, const unsigned* __restrict__ edges,
                      const __hip_bfloat16* __restrict__ sup, const float* __restrict__ bias,
                      const float* __restrict__ W, __hip_bfloat16* __restrict__ outS, int N) {
    constexpr int VPT = MA / GA;      // = 8
    static_assert(VPT == 8, "agg phase assumes 8 bf16 per lane");
    constexpr int NPB = 256 / GA;     // nodes per block (32 or 64)
    constexpr int KH = MA / 32, CTB = MB / 16, TILES = NPB / 16;
    static_assert(TILES * CTB == 4, "4 waves must cover (tile,ct) space");
    constexpr int STR = MA + 8;       // LDS row stride in bf16
    constexpr int EB = 8, NE = EB / GA;

    __shared__ float WsF[MA * MB];
    __shared__ unsigned short atile[NPB][STR];

    for (int i = threadIdx.x; i < MA * MB / 4; i += 256)
        reinterpret_cast<float4*>(WsF)[i] = reinterpret_cast<const float4*>(W)[i];

    int tid = threadIdx.x;
    int lr = tid / GA;
    int g = tid & (GA - 1);
    int node = blockIdx.x * NPB + lr;

    float acc[VPT];
#pragma unroll
    for (int j = 0; j < VPT; ++j) acc[j] = bias[g * VPT + j];

    if (node < N) {
        int beg = node ? rs[node - 1] : 0;
        int end = rs[node];
        const unsigned short* su = reinterpret_cast<const unsigned short*>(sup) + g * VPT;
        for (int j0 = beg; j0 < end; j0 += EB) {
            unsigned p[NE];
#pragma unroll
            for (int k = 0; k < NE; ++k) {
                int jl = j0 + k * GA + g;
                p[k] = edges[jl < end ? jl : end - 1];
            }
            int cnt = min(EB, end - j0);
            uint4 gv[EB];
            float wv[EB];
#pragma unroll
            for (int jj = 0; jj < EB; ++jj) {
                unsigned pe = __shfl(p[jj / GA], jj % GA, GA);
                wv[jj] = (float)(pe >> 17) * (1.0f / 32768.f);
                unsigned col = pe & 0x1FFFFu;
                if (jj < cnt)
                    gv[jj] = *reinterpret_cast<const uint4*>(su + (size_t)col * MA);
            }
#pragma unroll
            for (int jj = 0; jj < EB; ++jj) {
                if (jj >= cnt) break;
                float w = wv[jj];
                acc[0] += w * bflo(gv[jj].x); acc[1] += w * bfhi(gv[jj].x);
                acc[2] += w * bflo(gv[jj].y); acc[3] += w * bfhi(gv[jj].y);
                acc[4] += w * bflo(gv[jj].z); acc[5] += w * bfhi(gv[jj].z);
                acc[6] += w * bflo(gv[jj].w); acc[7] += w * bfhi(gv[jj].w);
            }
        }
    }
#pragma unroll
    for (int j = 0; j < VPT; ++j) acc[j] = lrelu(acc[j]);
    uint4 pk = { packbf(acc[0], acc[1]), packbf(acc[2], acc[3]),
                 packbf(acc[4], acc[5]), packbf(acc[6], acc[7]) };
    *reinterpret_cast<uint4*>(&atile[lr][g * 8]) = pk;
    __syncthreads();

    const int lane = tid & 63;
    const int wave = tid >> 6;
    const int tile = wave / CTB;
    const int ct = wave % CTB;
    const int lrow = lane & 15;
    const int lgrp = lane >> 4;

    bf16x8 bfrag[KH];
#pragma unroll
    for (int kh = 0; kh < KH; ++kh)
#pragma unroll
        for (int j = 0; j < 8; ++j)
            bfrag[kh][j] = (short)f2bf(WsF[(kh * 32 + lgrp * 8 + j) * MB + ct * 16 + lrow]);

    int nb = blockIdx.x * NPB + tile * 16;
    if (nb >= N) return;
    bf16x8 afrag[KH];
#pragma unroll
    for (int kh = 0; kh < KH; ++kh)
        afrag[kh] = *reinterpret_cast<const bf16x8*>(&atile[tile * 16 + lrow][kh * 32 + lgrp * 8]);

    f32x4 a = {0.f, 0.f, 0.f, 0.f};
#pragma unroll
    for (int kh = 0; kh < KH; ++kh)
        a = __builtin_amdgcn_mfma_f32_16x16x32_bf16(afrag[kh], bfrag[kh], a, 0, 0, 0);

    unsigned short* outs = (unsigned short*)outS;
#pragma unroll
    for (int r = 0; r < 4; ++r) {
        int orow = nb + lgrp * 4 + r;
        outs[(size_t)orow * MB + ct * 16 + lrow] = f2bf(a[r]);
    }
}

// ---------------- final CSR aggregation (layer 3, unchanged) ----------------

template <int M, int G, bool ACTOUT>
__global__ void __launch_bounds__(256)
agg_kernel(const int* __restrict__ rs, const unsigned* __restrict__ edges,
           const __hip_bfloat16* __restrict__ sup, const float* __restrict__ b,
           float* __restrict__ out, int N) {
    constexpr int VPT = M / G;       // 4
    constexpr int EB = 8;
    constexpr int NE = EB / G;
    int tid = blockIdx.x * blockDim.x + threadIdx.x;
    int node = tid / G;
    if (node >= N) return;
    int g = tid - node * G;

    float acc[VPT];
#pragma unroll
    for (int j = 0; j < VPT; ++j) acc[j] = b[g * VPT + j];

    int beg = node ? rs[node - 1] : 0;
    int end = rs[node];
    const unsigned short* su = reinterpret_cast<const unsigned short*>(sup) + g * VPT;

    for (int j0 = beg; j0 < end; j0 += EB) {
        unsigned p[NE];
#pragma unroll
        for (int k = 0; k < NE; ++k) {
            int jl = j0 + k * G + g;
            p[k] = edges[jl < end ? jl : end - 1];
        }
        int cnt = min(EB, end - j0);
        uint2 gv[EB];
        float wv[EB];
#pragma unroll
        for (int jj = 0; jj < EB; ++jj) {
            unsigned pe = __shfl(p[jj / G], jj % G, G);
            wv[jj] = (float)(pe >> 17) * (1.0f / 32768.f);
            unsigned col = pe & 0x1FFFFu;
            if (jj < cnt)
                gv[jj] = *reinterpret_cast<const uint2*>(su + (size_t)col * M);
        }
#pragma unroll
        for (int jj = 0; jj < EB; ++jj) {
            if (jj >= cnt) break;
            float w = wv[jj];
            acc[0] += w * bflo(gv[jj].x); acc[1] += w * bfhi(gv[jj].x);
            acc[2] += w * bflo(gv[jj].y); acc[3] += w * bfhi(gv[jj].y);
        }
    }
    if (ACTOUT) {
#pragma unroll
        for (int j = 0; j < VPT; ++j) acc[j] = lrelu(acc[j]);
    }
    float4 o = {acc[0], acc[1], acc[2], acc[3]};
    *reinterpret_cast<float4*>(out + (size_t)node * M + g * 4) = o;
}

extern "C" void kernel_launch(void* const* d_in, const int* in_sizes, int n_in,
                              void* d_out, int out_size, void* d_ws, size_t ws_size,
                              hipStream_t stream) {
    const float* x    = (const float*)d_in[0];
    const int*   erow = (const int*)  d_in[1];
    const int*   ecol = (const int*)  d_in[2];
    const float* ew   = (const float*)d_in[3];
    const float* W1   = (const float*)d_in[4];
    const float* b1   = (const float*)d_in[5];
    const float* W2   = (const float*)d_in[6];
    const float* b2   = (const float*)d_in[7];
    const float* W3   = (const float*)d_in[8];
    const float* b3   = (const float*)d_in[9];
    float* out = (float*)d_out;

    const int N = in_sizes[0] / 64;   // 100000
    const int E = in_sizes[1];        // 1000000

    auto cdiv = [](long a, long b) { return (int)((a + b - 1) / b); };
    const int NB   = cdiv(E, CHUNK);          // 489 edge chunks
    const int nbkt = cdiv(N, BKTSZ);          // 782 buckets
    const long T   = (long)nbkt * NB;         // 382,398 flat hist entries
    const int nsc  = cdiv(T, SCAN_CHUNK);     // 187 scan chunks (<= MAXNSC=256)

    // Workspace:
    //   [0,      12.8MB)  s1 (N*64 bf16)
    //   [12.8,   19.2MB)  s2 (N*32 bf16)
    //   [19.2,   22.4MB)  s3 (N*16 bf16)
    //   [22.4MB, ...)     I[T] (1.5MB), bsum[256], rs[N] (0.4MB),
    //                     eb1[E] int2 (8MB), edges[E] uint (4MB)
    char* wsc = (char*)d_ws;
    const size_t SZ64B = (size_t)N * 64 * 2;   // 12.8 MB
    const size_t SZ32B = (size_t)N * 32 * 2;   // 6.4 MB
    const size_t SZ16B = (size_t)N * 16 * 2;   // 3.2 MB
    __hip_bfloat16* s1 = (__hip_bfloat16*)(wsc);
    __hip_bfloat16* s2 = (__hip_bfloat16*)(wsc + SZ64B);
    __hip_bfloat16* s3 = (__hip_bfloat16*)(wsc + SZ64B + SZ32B);

    char* csr = wsc + SZ64B + SZ32B + SZ16B;
    int*      I     = (int*)csr;                   // T ints
    int*      bsum  = I + T;                       // MAXNSC ints
    int*      rs    = bsum + MAXNSC;               // N ints
    int2*     eb1   = (int2*)(rs + N);             // E int2
    unsigned* edges = (unsigned*)(eb1 + E);        // E uint (4B packed)

    const int B = 256;
    const int GB = cdiv(N, 128);                   // gemm1 blocks (NT=2, 128 nodes/blk)

    // ---- CSR build; gemm1 overlapped with place1 ----
    hist1_kernel<<<NB, B, 0, stream>>>(erow, I, E, nbkt, NB);
    scan1_kernel<<<nsc, SCAN_T, 0, stream>>>(I, bsum, (int)T);
    fused_place1_gemm1_kernel<<<NB + GB, B, 0, stream>>>(
        erow, ecol, ew, I, bsum, nsc, eb1, E, nbkt, NB, x, W1, s1, N);
    place2_kernel<<<nbkt, B, 0, stream>>>(eb1, I, bsum, nsc, edges, rs, N, NB);

    // ---- agg1 + gemm2 fused: s1 --agg--> LDS --@W2--> s2 ----
    fused_agg_gemm_kernel<64, 8, 32><<<cdiv(N, 32), B, 0, stream>>>(
        rs, edges, s1, b1, W2, s2, N);

    // ---- agg2 + gemm3 fused: s2 --agg--> LDS --@W3--> s3 ----
    fused_agg_gemm_kernel<32, 4, 16><<<cdiv(N, 64), B, 0, stream>>>(
        rs, edges, s2, b2, W3, s3, N);

    // ---- agg3: final aggregation + lrelu -> f32 out ----
    agg_kernel<16, 4, true><<<cdiv((long)N * 4, B), B, 0, stream>>>(rs, edges, s3, b3, out, N);
}

// Round 16
// 92.320 us; speedup vs baseline: 1.0604x; 1.0604x over previous
//
#include <hip/hip_runtime.h>
#include <hip/hip_bf16.h>

// 3-layer GCN, N=100000, E=1000000, dims 64 -> 64 -> 32 -> 16.
// CSR via two-level LDS bucket counting sort (zero global atomics).
// R16: revert R15's CHUNK=2048 (regression: per-block fixed costs dominate
// these kernels, not occupancy). Back to R14 config (CHUNK=4096, MAXNSC=128),
// plus int4-vectorized row reads in hist1.

typedef short bf16x8 __attribute__((ext_vector_type(8)));
typedef float f32x4 __attribute__((ext_vector_type(4)));

__device__ __forceinline__ float lrelu(float v) { return v > 0.0f ? v : 0.25f * v; }
__device__ __forceinline__ float bflo(unsigned u) { return __uint_as_float(u << 16); }
__device__ __forceinline__ float bfhi(unsigned u) { return __uint_as_float(u & 0xffff0000u); }
__device__ __forceinline__ unsigned short f2bf(float f) {          // round-to-nearest-even
    unsigned u = __float_as_uint(f);
    return (unsigned short)((u + 0x7fffu + ((u >> 16) & 1u)) >> 16);
}
__device__ __forceinline__ unsigned packbf(float a, float b) {
    return (unsigned)f2bf(a) | ((unsigned)f2bf(b) << 16);
}

// ---------------- bucket counting-sort CSR build ----------------

constexpr int SCAN_T = 256;
constexpr int SCAN_PER = 8;
constexpr int SCAN_CHUNK = SCAN_T * SCAN_PER;  // 2048 (scan1 granularity; getI >>11)
constexpr int CHUNK = 4096;                    // edges per hist/place1 block
constexpr int BKT_BITS = 7;
constexpr int BKTSZ = 128;                     // nodes per bucket
constexpr int MAXBKT = 1024;                   // LDS bins (N <= 131072)
constexpr int MAXNSC = 128;                    // max scan1 chunks (T <= 262144)
constexpr int P2CAP = 2048;                    // place2 LDS edge cap (avg 1280/bucket)

__device__ __forceinline__ void build_bofs(const int* __restrict__ bsum, int nsc,
                                           int* tmp, int* bofs) {
    int t = threadIdx.x;
    int v = (t < MAXNSC && t < nsc) ? bsum[t] : 0;
    if (t < MAXNSC) tmp[t] = v;
    __syncthreads();
    for (int off = 1; off < MAXNSC; off <<= 1) {
        int add = (t < MAXNSC && t >= off) ? tmp[t - off] : 0;
        __syncthreads();
        if (t < MAXNSC) tmp[t] += add;
        __syncthreads();
    }
    if (t < MAXNSC) bofs[t] = tmp[t] - v;   // exclusive
    __syncthreads();
}

__device__ __forceinline__ int getI(const int* __restrict__ I,
                                    const int* __restrict__ bofs, size_t idx) {
    return I[idx] + bofs[idx >> 11];    // 2048-element scan chunks
}

__global__ void __launch_bounds__(256)
hist1_kernel(const int* __restrict__ row, int* __restrict__ hists,
             int E, int nbkt, int NB) {
    __shared__ int hist[MAXBKT];
    for (int i = threadIdx.x; i < nbkt; i += 256) hist[i] = 0;
    __syncthreads();
    int e0 = blockIdx.x * CHUNK;
    int e1 = min(e0 + CHUNK, E);
    if (e1 - e0 == CHUNK && ((e0 & 3) == 0)) {           // full chunk: int4 reads
        const int4* r4 = reinterpret_cast<const int4*>(row + e0);
        for (int q = threadIdx.x; q < CHUNK / 4; q += 256) {
            int4 v = r4[q];
            atomicAdd(&hist[v.x >> BKT_BITS], 1);
            atomicAdd(&hist[v.y >> BKT_BITS], 1);
            atomicAdd(&hist[v.z >> BKT_BITS], 1);
            atomicAdd(&hist[v.w >> BKT_BITS], 1);
        }
    } else {
        for (int e = e0 + threadIdx.x; e < e1; e += 256)
            atomicAdd(&hist[row[e] >> BKT_BITS], 1);     // LDS atomic
    }
    __syncthreads();
    for (int i = threadIdx.x; i < nbkt; i += 256)
        hists[(size_t)i * NB + blockIdx.x] = hist[i];
}

__global__ void __launch_bounds__(SCAN_T)
scan1_kernel(int* __restrict__ I, int* __restrict__ bsum, int T) {
    __shared__ int lds[SCAN_T];
    int t = threadIdx.x;
    int base = blockIdx.x * SCAN_CHUNK + t * SCAN_PER;
    int v[SCAN_PER];
    int run = 0;
#pragma unroll
    for (int j = 0; j < SCAN_PER; ++j) {
        int i = base + j;
        run += (i < T) ? I[i] : 0;
        v[j] = run;
    }
    lds[t] = run;
    __syncthreads();
    for (int off = 1; off < SCAN_T; off <<= 1) {
        int add = (t >= off) ? lds[t - off] : 0;
        __syncthreads();
        lds[t] += add;
        __syncthreads();
    }
    int excl = lds[t] - run;
#pragma unroll
    for (int j = 0; j < SCAN_PER; ++j) {
        int i = base + j;
        if (i < T) I[i] = v[j] + excl;
    }
    if (t == SCAN_T - 1) bsum[blockIdx.x] = lds[t];
}

// ---------------- fused: place1 (blocks [0,NB)) + MFMA gemm1 (blocks [NB,..)) ----

__global__ void __launch_bounds__(256)
fused_place1_gemm1_kernel(const int* __restrict__ row, const int* __restrict__ col,
                          const float* __restrict__ w, const int* __restrict__ I,
                          const int* __restrict__ bsum, int nsc, int2* __restrict__ eb1,
                          int E, int nbkt, int NB,
                          const float* __restrict__ x, const float* __restrict__ W1,
                          __hip_bfloat16* __restrict__ s1, int N) {
    __shared__ int arena[CHUNK + MAXBKT + 2 * MAXNSC];   // 21.5 KB
    if ((int)blockIdx.x < NB) {
        // ---- place1 role ----
        int* srow = arena;
        int* hist = arena + CHUNK;
        int* tmp  = arena + CHUNK + MAXBKT;
        int* bofs = tmp + MAXNSC;
        build_bofs(bsum, nsc, tmp, bofs);
        for (int i = threadIdx.x; i < nbkt; i += 256) hist[i] = 0;
        int e0 = blockIdx.x * CHUNK;
        int e1 = min(e0 + CHUNK, E);
        for (int e = e0 + threadIdx.x; e < e1; e += 256) srow[e - e0] = row[e];
        __syncthreads();
        for (int i = threadIdx.x; i < e1 - e0; i += 256)
            atomicAdd(&hist[srow[i] >> BKT_BITS], 1);
        __syncthreads();
        for (int i = threadIdx.x; i < nbkt; i += 256) {
            size_t idx = (size_t)i * NB + blockIdx.x;
            hist[i] = getI(I, bofs, idx) - hist[i];
        }
        __syncthreads();
        for (int e = e0 + threadIdx.x; e < e1; e += 256) {
            int r = srow[e - e0];
            int pos = atomicAdd(&hist[r >> BKT_BITS], 1);    // LDS atomic, returns slot
            eb1[pos] = make_int2(((r & (BKTSZ - 1)) << 20) | col[e], __float_as_int(w[e]));
        }
        return;
    }
    // ---- MFMA gemm1 role: s1 = bf16(x) @ W1, K=64, M=64, NT=2 ----
    constexpr int K = 64, M = 64, NT = 2, CT = M / 16, KH = K / 32;
    float* Ws = reinterpret_cast<float*>(arena);
    for (int i = threadIdx.x; i < K * M / 4; i += 256)
        reinterpret_cast<float4*>(Ws)[i] = reinterpret_cast<const float4*>(W1)[i];
    __syncthreads();
    const int lane = threadIdx.x & 63;
    const int wave = threadIdx.x >> 6;
    const int lrow = lane & 15;
    const int lgrp = lane >> 4;

    bf16x8 bfrag[CT][KH];
#pragma unroll
    for (int ct = 0; ct < CT; ++ct)
#pragma unroll
        for (int kh = 0; kh < KH; ++kh)
#pragma unroll
            for (int j = 0; j < 8; ++j)
                bfrag[ct][kh][j] =
                    (short)f2bf(Ws[(kh * 32 + lgrp * 8 + j) * M + ct * 16 + lrow]);

    unsigned short* outs = (unsigned short*)s1;
    const int wave_base = ((int)blockIdx.x - NB) * (4 * NT * 16) + wave * (NT * 16);
#pragma unroll
    for (int t = 0; t < NT; ++t) {
        int nb = wave_base + t * 16;
        if (nb >= N) break;
        int arow = nb + lrow;
        bf16x8 afrag[KH];
#pragma unroll
        for (int kh = 0; kh < KH; ++kh) {
            const float* ap = x + (size_t)arow * K + kh * 32 + lgrp * 8;
            float4 u0 = *reinterpret_cast<const float4*>(ap);
            float4 u1 = *reinterpret_cast<const float4*>(ap + 4);
            afrag[kh][0] = (short)f2bf(u0.x); afrag[kh][1] = (short)f2bf(u0.y);
            afrag[kh][2] = (short)f2bf(u0.z); afrag[kh][3] = (short)f2bf(u0.w);
            afrag[kh][4] = (short)f2bf(u1.x); afrag[kh][5] = (short)f2bf(u1.y);
            afrag[kh][6] = (short)f2bf(u1.z); afrag[kh][7] = (short)f2bf(u1.w);
        }
        f32x4 acc[CT];
#pragma unroll
        for (int ct = 0; ct < CT; ++ct) { acc[ct][0]=0.f; acc[ct][1]=0.f; acc[ct][2]=0.f; acc[ct][3]=0.f; }
#pragma unroll
        for (int ct = 0; ct < CT; ++ct)
#pragma unroll
            for (int kh = 0; kh < KH; ++kh)
                acc[ct] = __builtin_amdgcn_mfma_f32_16x16x32_bf16(
                    afrag[kh], bfrag[ct][kh], acc[ct], 0, 0, 0);
#pragma unroll
        for (int ct = 0; ct < CT; ++ct)
#pragma unroll
            for (int r = 0; r < 4; ++r) {
                int orow = nb + lgrp * 4 + r;
                outs[(size_t)orow * M + ct * 16 + lrow] = f2bf(acc[ct][r]);
            }
    }
}

// one block per bucket: LDS-staged single-pass per-node CSR; emits packed edges[] + rs[].
__global__ void __launch_bounds__(256)
place2_kernel(const int2* __restrict__ eb1, const int* __restrict__ I,
              const int* __restrict__ bsum, int nsc, unsigned* __restrict__ edges,
              int* __restrict__ rs, int N, int NB) {
    __shared__ int2 se[P2CAP];        // 16 KB staged edges
    __shared__ int hist[BKTSZ];
    __shared__ int scanv[BKTSZ];
    __shared__ int tmp[MAXNSC];
    __shared__ int bofs[MAXNSC];
    build_bofs(bsum, nsc, tmp, bofs);
    int b = blockIdx.x;
    int t = threadIdx.x;
    int bstart = (b == 0) ? 0 : getI(I, bofs, (size_t)b * NB - 1);
    int bend   = getI(I, bofs, (size_t)(b + 1) * NB - 1);
    int cnt = bend - bstart;
    bool inlds = (cnt <= P2CAP);
    if (inlds)
        for (int e = t; e < cnt; e += 256) se[e] = eb1[bstart + e];   // one coalesced read
    if (t < BKTSZ) hist[t] = 0;
    __syncthreads();
    for (int e = t; e < cnt; e += 256) {
        int ex = inlds ? se[e].x : eb1[bstart + e].x;
        atomicAdd(&hist[(ex >> 20) & (BKTSZ - 1)], 1);
    }
    __syncthreads();
    int cval = (t < BKTSZ) ? hist[t] : 0;
    if (t < BKTSZ) scanv[t] = cval;
    __syncthreads();
    for (int off = 1; off < BKTSZ; off <<= 1) {
        int add = (t < BKTSZ && t >= off) ? scanv[t - off] : 0;
        __syncthreads();
        if (t < BKTSZ) scanv[t] += add;
        __syncthreads();
    }
    if (t < BKTSZ) {
        int gnode = b * BKTSZ + t;
        if (gnode < N) rs[gnode] = bstart + scanv[t];        // inclusive ends
        hist[t] = bstart + scanv[t] - cval;                  // node base for placing
    }
    __syncthreads();
    for (int e = t; e < cnt; e += 256) {
        int2 ev = inlds ? se[e] : eb1[bstart + e];
        int lrow = (ev.x >> 20) & (BKTSZ - 1);
        float w = __int_as_float(ev.y);
        unsigned q = (unsigned)(w * 32768.f + 0.5f);
        q = q > 32767u ? 32767u : q;
        unsigned packed = (q << 17) | (unsigned)(ev.x & 0x1FFFF);   // w15 | col17
        int pos = atomicAdd(&hist[lrow], 1);                 // LDS atomic
        edges[pos] = packed;
    }
}

// ---------------- fused agg_k + gemm_{k+1} (unchanged) ----------------

template <int MA, int GA, int MB>
__global__ void __launch_bounds__(256)
fused_agg_gemm_kernel(const int* __restrict__ rs, const unsigned* __restrict__ edges,
                      const __hip_bfloat16* __restrict__ sup, const float* __restrict__ bias,
                      const float* __restrict__ W, __hip_bfloat16* __restrict__ outS, int N) {
    constexpr int VPT = MA / GA;      // = 8
    static_assert(VPT == 8, "agg phase assumes 8 bf16 per lane");
    constexpr int NPB = 256 / GA;     // nodes per block (32 or 64)
    constexpr int KH = MA / 32, CTB = MB / 16, TILES = NPB / 16;
    static_assert(TILES * CTB == 4, "4 waves must cover (tile,ct) space");
    constexpr int STR = MA + 8;       // LDS row stride in bf16
    constexpr int EB = 8, NE = EB / GA;

    __shared__ float WsF[MA * MB];
    __shared__ unsigned short atile[NPB][STR];

    for (int i = threadIdx.x; i < MA * MB / 4; i += 256)
        reinterpret_cast<float4*>(WsF)[i] = reinterpret_cast<const float4*>(W)[i];

    int tid = threadIdx.x;
    int lr = tid / GA;
    int g = tid & (GA - 1);
    int node = blockIdx.x * NPB + lr;

    float acc[VPT];
#pragma unroll
    for (int j = 0; j < VPT; ++j) acc[j] = bias[g * VPT + j];

    if (node < N) {
        int beg = node ? rs[node - 1] : 0;
        int end = rs[node];
        const unsigned short* su = reinterpret_cast<const unsigned short*>(sup) + g * VPT;
        for (int j0 = beg; j0 < end; j0 += EB) {
            unsigned p[NE];
#pragma unroll
            for (int k = 0; k < NE; ++k) {
                int jl = j0 + k * GA + g;
                p[k] = edges[jl < end ? jl : end - 1];
            }
            int cnt = min(EB, end - j0);
            uint4 gv[EB];
            float wv[EB];
#pragma unroll
            for (int jj = 0; jj < EB; ++jj) {
                unsigned pe = __shfl(p[jj / GA], jj % GA, GA);
                wv[jj] = (float)(pe >> 17) * (1.0f / 32768.f);
                unsigned col = pe & 0x1FFFFu;
                if (jj < cnt)
                    gv[jj] = *reinterpret_cast<const uint4*>(su + (size_t)col * MA);
            }
#pragma unroll
            for (int jj = 0; jj < EB; ++jj) {
                if (jj >= cnt) break;
                float w = wv[jj];
                acc[0] += w * bflo(gv[jj].x); acc[1] += w * bfhi(gv[jj].x);
                acc[2] += w * bflo(gv[jj].y); acc[3] += w * bfhi(gv[jj].y);
                acc[4] += w * bflo(gv[jj].z); acc[5] += w * bfhi(gv[jj].z);
                acc[6] += w * bflo(gv[jj].w); acc[7] += w * bfhi(gv[jj].w);
            }
        }
    }
#pragma unroll
    for (int j = 0; j < VPT; ++j) acc[j] = lrelu(acc[j]);
    uint4 pk = { packbf(acc[0], acc[1]), packbf(acc[2], acc[3]),
                 packbf(acc[4], acc[5]), packbf(acc[6], acc[7]) };
    *reinterpret_cast<uint4*>(&atile[lr][g * 8]) = pk;
    __syncthreads();

    const int lane = tid & 63;
    const int wave = tid >> 6;
    const int tile = wave / CTB;
    const int ct = wave % CTB;
    const int lrow = lane & 15;
    const int lgrp = lane >> 4;

    bf16x8 bfrag[KH];
#pragma unroll
    for (int kh = 0; kh < KH; ++kh)
#pragma unroll
        for (int j = 0; j < 8; ++j)
            bfrag[kh][j] = (short)f2bf(WsF[(kh * 32 + lgrp * 8 + j) * MB + ct * 16 + lrow]);

    int nb = blockIdx.x * NPB + tile * 16;
    if (nb >= N) return;
    bf16x8 afrag[KH];
#pragma unroll
    for (int kh = 0; kh < KH; ++kh)
        afrag[kh] = *reinterpret_cast<const bf16x8*>(&atile[tile * 16 + lrow][kh * 32 + lgrp * 8]);

    f32x4 a = {0.f, 0.f, 0.f, 0.f};
#pragma unroll
    for (int kh = 0; kh < KH; ++kh)
        a = __builtin_amdgcn_mfma_f32_16x16x32_bf16(afrag[kh], bfrag[kh], a, 0, 0, 0);

    unsigned short* outs = (unsigned short*)outS;
#pragma unroll
    for (int r = 0; r < 4; ++r) {
        int orow = nb + lgrp * 4 + r;
        outs[(size_t)orow * MB + ct * 16 + lrow] = f2bf(a[r]);
    }
}

// ---------------- final CSR aggregation (layer 3, unchanged) ----------------

template <int M, int G, bool ACTOUT>
__global__ void __launch_bounds__(256)
agg_kernel(const int* __restrict__ rs, const unsigned* __restrict__ edges,
           const __hip_bfloat16* __restrict__ sup, const float* __restrict__ b,
           float* __restrict__ out, int N) {
    constexpr int VPT = M / G;       // 4
    constexpr int EB = 8;
    constexpr int NE = EB / G;
    int tid = blockIdx.x * blockDim.x + threadIdx.x;
    int node = tid / G;
    if (node >= N) return;
    int g = tid - node * G;

    float acc[VPT];
#pragma unroll
    for (int j = 0; j < VPT; ++j) acc[j] = b[g * VPT + j];

    int beg = node ? rs[node - 1] : 0;
    int end = rs[node];
    const unsigned short* su = reinterpret_cast<const unsigned short*>(sup) + g * VPT;

    for (int j0 = beg; j0 < end; j0 += EB) {
        unsigned p[NE];
#pragma unroll
        for (int k = 0; k < NE; ++k) {
            int jl = j0 + k * G + g;
            p[k] = edges[jl < end ? jl : end - 1];
        }
        int cnt = min(EB, end - j0);
        uint2 gv[EB];
        float wv[EB];
#pragma unroll
        for (int jj = 0; jj < EB; ++jj) {
            unsigned pe = __shfl(p[jj / G], jj % G, G);
            wv[jj] = (float)(pe >> 17) * (1.0f / 32768.f);
            unsigned col = pe & 0x1FFFFu;
            if (jj < cnt)
                gv[jj] = *reinterpret_cast<const uint2*>(su + (size_t)col * M);
        }
#pragma unroll
        for (int jj = 0; jj < EB; ++jj) {
            if (jj >= cnt) break;
            float w = wv[jj];
            acc[0] += w * bflo(gv[jj].x); acc[1] += w * bfhi(gv[jj].x);
            acc[2] += w * bflo(gv[jj].y); acc[3] += w * bfhi(gv[jj].y);
        }
    }
    if (ACTOUT) {
#pragma unroll
        for (int j = 0; j < VPT; ++j) acc[j] = lrelu(acc[j]);
    }
    float4 o = {acc[0], acc[1], acc[2], acc[3]};
    *reinterpret_cast<float4*>(out + (size_t)node * M + g * 4) = o;
}

extern "C" void kernel_launch(void* const* d_in, const int* in_sizes, int n_in,
                              void* d_out, int out_size, void* d_ws, size_t ws_size,
                              hipStream_t stream) {
    const float* x    = (const float*)d_in[0];
    const int*   erow = (const int*)  d_in[1];
    const int*   ecol = (const int*)  d_in[2];
    const float* ew   = (const float*)d_in[3];
    const float* W1   = (const float*)d_in[4];
    const float* b1   = (const float*)d_in[5];
    const float* W2   = (const float*)d_in[6];
    const float* b2   = (const float*)d_in[7];
    const float* W3   = (const float*)d_in[8];
    const float* b3   = (const float*)d_in[9];
    float* out = (float*)d_out;

    const int N = in_sizes[0] / 64;   // 100000
    const int E = in_sizes[1];        // 1000000

    auto cdiv = [](long a, long b) { return (int)((a + b - 1) / b); };
    const int NB   = cdiv(E, CHUNK);          // 245 edge chunks
    const int nbkt = cdiv(N, BKTSZ);          // 782 buckets
    const long T   = (long)nbkt * NB;         // 191,590 flat hist entries
    const int nsc  = cdiv(T, SCAN_CHUNK);     // 94 scan chunks (<= MAXNSC)

    // Workspace:
    //   [0,      12.8MB)  s1 (N*64 bf16)
    //   [12.8,   19.2MB)  s2 (N*32 bf16)
    //   [19.2,   22.4MB)  s3 (N*16 bf16)
    //   [22.4MB, ...)     I[T] (0.8MB), bsum[128], rs[N] (0.4MB),
    //                     eb1[E] int2 (8MB), edges[E] uint (4MB)
    char* wsc = (char*)d_ws;
    const size_t SZ64B = (size_t)N * 64 * 2;   // 12.8 MB
    const size_t SZ32B = (size_t)N * 32 * 2;   // 6.4 MB
    const size_t SZ16B = (size_t)N * 16 * 2;   // 3.2 MB
    __hip_bfloat16* s1 = (__hip_bfloat16*)(wsc);
    __hip_bfloat16* s2 = (__hip_bfloat16*)(wsc + SZ64B);
    __hip_bfloat16* s3 = (__hip_bfloat16*)(wsc + SZ64B + SZ32B);

    char* csr = wsc + SZ64B + SZ32B + SZ16B;
    int*      I     = (int*)csr;                   // T ints
    int*      bsum  = I + T;                       // MAXNSC ints
    int*      rs    = bsum + MAXNSC;               // N ints
    int2*     eb1   = (int2*)(rs + N);             // E int2
    unsigned* edges = (unsigned*)(eb1 + E);        // E uint (4B packed)

    const int B = 256;
    const int GB = cdiv(N, 128);                   // gemm1 blocks (NT=2, 128 nodes/blk)

    // ---- CSR build; gemm1 overlapped with place1 ----
    hist1_kernel<<<NB, B, 0, stream>>>(erow, I, E, nbkt, NB);
    scan1_kernel<<<nsc, SCAN_T, 0, stream>>>(I, bsum, (int)T);
    fused_place1_gemm1_kernel<<<NB + GB, B, 0, stream>>>(
        erow, ecol, ew, I, bsum, nsc, eb1, E, nbkt, NB, x, W1, s1, N);
    place2_kernel<<<nbkt, B, 0, stream>>>(eb1, I, bsum, nsc, edges, rs, N, NB);

    // ---- agg1 + gemm2 fused: s1 --agg--> LDS --@W2--> s2 ----
    fused_agg_gemm_kernel<64, 8, 32><<<cdiv(N, 32), B, 0, stream>>>(
        rs, edges, s1, b1, W2, s2, N);

    // ---- agg2 + gemm3 fused: s2 --agg--> LDS --@W3--> s3 ----
    fused_agg_gemm_kernel<32, 4, 16><<<cdiv(N, 64), B, 0, stream>>>(
        rs, edges, s2, b2, W3, s3, N);

    // ---- agg3: final aggregation + lrelu -> f32 out ----
    agg_kernel<16, 4, true><<<cdiv((long)N * 4, B), B, 0, stream>>>(rs, edges, s3, b3, out, N);
}